// Round 2
// baseline (116.563 us; speedup 1.0000x reference)
//
#include <hip/hip_runtime.h>

#define N_RAYS   65536
#define NS       256
#define NSM1     255
#define EPS_V    1e-5f

__device__ __forceinline__ float fast_rcp(float x) {
    return __builtin_amdgcn_rcpf(x);
}

// fast sigmoid(x) = 1/(1+exp(-x)) using native exp2 + rcp
__device__ __forceinline__ float fast_sigmoid(float x) {
    // exp(-x) = exp2(-x * log2(e))
    float e = __builtin_amdgcn_exp2f(-x * 1.442695041f);
    return fast_rcp(1.0f + e);
}

__global__ __launch_bounds__(256) void nerf_render_kernel(
    const float* __restrict__ t,
    const float* __restrict__ sdf,
    const float* __restrict__ color,
    const float* __restrict__ s_inv_log,
    float* __restrict__ out)
{
    const int lane = threadIdx.x & 63;
    const int wave = threadIdx.x >> 6;
    const int ray  = blockIdx.x * 4 + wave;

    float* __restrict__ c_out  = out;                               // 65536*3
    float* __restrict__ d_out  = out + (size_t)N_RAYS * 3;          // 65536
    float* __restrict__ wi_out = out + (size_t)N_RAYS * 4;          // 65536*255
    float* __restrict__ t_out  = wi_out + (size_t)N_RAYS * NSM1;    // 65536*255

    const float s = expf(-s_inv_log[0]);

    const size_t base = (size_t)ray * NS + (size_t)lane * 4;

    // Issue all global loads up front (no dependencies between them).
    const float4 sd = *reinterpret_cast<const float4*>(sdf + base);
    const float4 tv = *reinterpret_cast<const float4*>(t   + base);
    const float4* cp = reinterpret_cast<const float4*>(color + base * 3);
    const float4 c0 = cp[0];
    const float4 c1 = cp[1];
    const float4 c2 = cp[2];

    // q = sigmoid(sdf * s)  (native exp2 + rcp; accuracy budget is huge)
    float q[5];
    q[0] = fast_sigmoid(sd.x * s);
    q[1] = fast_sigmoid(sd.y * s);
    q[2] = fast_sigmoid(sd.z * s);
    q[3] = fast_sigmoid(sd.w * s);
    q[4] = __shfl_down(q[0], 1, 64);   // next lane's first q (unused on lane 63)

    float alpha[4], m[4];
    #pragma unroll
    for (int k = 0; k < 4; ++k) {
        float a = (q[k] - q[k + 1] + EPS_V) * fast_rcp(q[k] + EPS_V);
        a = fminf(fmaxf(a, 0.0f), 1.0f);
        if (lane == 63 && k == 3) a = 0.0f;   // sample 255 has no alpha
        alpha[k] = a;
        m[k] = 1.0f - a;
    }

    // In-lane exclusive prefix products of m
    float e[4];
    e[0] = 1.0f;
    e[1] = m[0];
    e[2] = e[1] * m[1];
    e[3] = e[2] * m[2];
    const float L = e[3] * m[3];   // local total product

    // Inclusive wave scan (product) of L across 64 lanes
    float p = L;
    #pragma unroll
    for (int off = 1; off < 64; off <<= 1) {
        float v = __shfl_up(p, off, 64);
        if (lane >= off) p *= v;
    }
    // Exclusive: product over lanes < l
    float Ew = __shfl_up(p, 1, 64);
    if (lane == 0) Ew = 1.0f;

    // wi = Ti * alpha, Ti[4l+k] = Ew * e[k]
    float wi[4];
    #pragma unroll
    for (int k = 0; k < 4; ++k) wi[k] = Ew * e[k] * alpha[k];

    // Stream out wi and t[:-1] with non-temporal stores (written once,
    // never re-read by the kernel: keep them from thrashing L2/L3 so the
    // 300 MB input set stays resident across replays).
    const size_t wbase = (size_t)ray * NSM1 + (size_t)lane * 4;
    const float tvk[4] = { tv.x, tv.y, tv.z, tv.w };
    const int nw = (lane == 63) ? 3 : 4;
    #pragma unroll
    for (int k = 0; k < 4; ++k) {
        if (k < nw) {
            __builtin_nontemporal_store(wi[k],  wi_out + wbase + k);
            __builtin_nontemporal_store(tvk[k], t_out  + wbase + k);
        }
    }

    // Per-lane partial sums
    const float c[12] = { c0.x, c0.y, c0.z, c0.w,
                          c1.x, c1.y, c1.z, c1.w,
                          c2.x, c2.y, c2.z, c2.w };
    float dsum = 0.0f, rs = 0.0f, gs = 0.0f, bs = 0.0f;
    #pragma unroll
    for (int k = 0; k < 4; ++k) {
        dsum += wi[k] * tvk[k];
        rs   += wi[k] * c[3 * k + 0];
        gs   += wi[k] * c[3 * k + 1];
        bs   += wi[k] * c[3 * k + 2];
    }

    // Wave reduction (64 lanes)
    #pragma unroll
    for (int off = 32; off > 0; off >>= 1) {
        dsum += __shfl_xor(dsum, off, 64);
        rs   += __shfl_xor(rs,   off, 64);
        gs   += __shfl_xor(gs,   off, 64);
        bs   += __shfl_xor(bs,   off, 64);
    }

    if (lane == 0) {
        c_out[(size_t)ray * 3 + 0] = rs;
        c_out[(size_t)ray * 3 + 1] = gs;
        c_out[(size_t)ray * 3 + 2] = bs;
        d_out[ray] = dsum;
    }
}

extern "C" void kernel_launch(void* const* d_in, const int* in_sizes, int n_in,
                              void* d_out, int out_size, void* d_ws, size_t ws_size,
                              hipStream_t stream) {
    const float* t     = (const float*)d_in[0];
    const float* sdf   = (const float*)d_in[1];
    const float* color = (const float*)d_in[2];
    const float* sil   = (const float*)d_in[3];
    float* out = (float*)d_out;

    const int blocks = N_RAYS / 4;   // 4 rays (waves) per 256-thread block
    nerf_render_kernel<<<blocks, 256, 0, stream>>>(t, sdf, color, sil, out);
}

// Round 3
// 92.601 us; speedup vs baseline: 1.2588x; 1.2588x over previous
//
#include <hip/hip_runtime.h>

#define N_RAYS   65536
#define NS       256
#define NSM1     255
#define EPS_V    1e-5f
#define RPW      2   // rays per wave

__device__ __forceinline__ float fast_rcp(float x) {
    return __builtin_amdgcn_rcpf(x);
}

// fast sigmoid(x) = 1/(1+exp(-x)) using native exp2 + rcp
__device__ __forceinline__ float fast_sigmoid(float x) {
    float e = __builtin_amdgcn_exp2f(-x * 1.442695041f);
    return fast_rcp(1.0f + e);
}

__global__ __launch_bounds__(256) void nerf_render_kernel(
    const float* __restrict__ t,
    const float* __restrict__ sdf,
    const float* __restrict__ color,
    const float* __restrict__ s_inv_log,
    float* __restrict__ out)
{
    const int lane = threadIdx.x & 63;
    const int wave = threadIdx.x >> 6;
    const int ray0 = blockIdx.x * (4 * RPW) + wave * RPW;

    float* __restrict__ c_out  = out;                               // 65536*3
    float* __restrict__ d_out  = out + (size_t)N_RAYS * 3;          // 65536
    float* __restrict__ wi_out = out + (size_t)N_RAYS * 4;          // 65536*255
    float* __restrict__ t_out  = wi_out + (size_t)N_RAYS * NSM1;    // 65536*255

    const float s = expf(-s_inv_log[0]);

    // ---- Stage 0: issue ALL global loads for both rays up front ----
    float4 sd[RPW], tv[RPW], c0[RPW], c1[RPW], c2[RPW];
    #pragma unroll
    for (int r = 0; r < RPW; ++r) {
        const size_t base = (size_t)(ray0 + r) * NS + (size_t)lane * 4;
        sd[r] = *reinterpret_cast<const float4*>(sdf + base);
        tv[r] = *reinterpret_cast<const float4*>(t   + base);
        const float4* cp = reinterpret_cast<const float4*>(color + base * 3);
        c0[r] = cp[0];
        c1[r] = cp[1];
        c2[r] = cp[2];
    }

    // ---- Stage 1: q = sigmoid(sdf * s), alpha, per-lane prefix ----
    float e[RPW][4], alpha[RPW][4], Lprod[RPW];
    #pragma unroll
    for (int r = 0; r < RPW; ++r) {
        float q[5];
        q[0] = fast_sigmoid(sd[r].x * s);
        q[1] = fast_sigmoid(sd[r].y * s);
        q[2] = fast_sigmoid(sd[r].z * s);
        q[3] = fast_sigmoid(sd[r].w * s);
        q[4] = __shfl_down(q[0], 1, 64);   // next lane's first q

        float m[4];
        #pragma unroll
        for (int k = 0; k < 4; ++k) {
            float a = (q[k] - q[k + 1] + EPS_V) * fast_rcp(q[k] + EPS_V);
            a = fminf(fmaxf(a, 0.0f), 1.0f);
            if (lane == 63 && k == 3) a = 0.0f;   // sample 255 has no alpha
            alpha[r][k] = a;
            m[k] = 1.0f - a;
        }
        e[r][0] = 1.0f;
        e[r][1] = m[0];
        e[r][2] = e[r][1] * m[1];
        e[r][3] = e[r][2] * m[2];
        Lprod[r] = e[r][3] * m[3];
    }

    // ---- Stage 2: wave-wide exclusive product scan (both rays interleaved:
    //      two independent 6-step chains -> 2x ILP on the serial latency) ----
    float p[RPW];
    #pragma unroll
    for (int r = 0; r < RPW; ++r) p[r] = Lprod[r];
    #pragma unroll
    for (int off = 1; off < 64; off <<= 1) {
        #pragma unroll
        for (int r = 0; r < RPW; ++r) {
            float v = __shfl_up(p[r], off, 64);
            if (lane >= off) p[r] *= v;
        }
    }
    float Ew[RPW];
    #pragma unroll
    for (int r = 0; r < RPW; ++r) {
        Ew[r] = __shfl_up(p[r], 1, 64);
        if (lane == 0) Ew[r] = 1.0f;
    }

    // ---- Stage 3: wi, streamed stores (plain cached stores; L2 merges the
    //      4 stride-16B partial-line writes -> WRITE_SIZE stays ~ideal) ----
    float wi[RPW][4];
    #pragma unroll
    for (int r = 0; r < RPW; ++r) {
        #pragma unroll
        for (int k = 0; k < 4; ++k) wi[r][k] = Ew[r] * e[r][k] * alpha[r][k];

        const size_t wbase = (size_t)(ray0 + r) * NSM1 + (size_t)lane * 4;
        const float tvk[4] = { tv[r].x, tv[r].y, tv[r].z, tv[r].w };
        const int nw = (lane == 63) ? 3 : 4;
        #pragma unroll
        for (int k = 0; k < 4; ++k) {
            if (k < nw) {
                wi_out[wbase + k] = wi[r][k];
                t_out [wbase + k] = tvk[k];
            }
        }
    }

    // ---- Stage 4: per-lane partial sums + wave butterfly (8 independent
    //      chains across r and {d,r,g,b} -> latency fully overlapped) ----
    float dsum[RPW], rs[RPW], gs[RPW], bs[RPW];
    #pragma unroll
    for (int r = 0; r < RPW; ++r) {
        const float c[12] = { c0[r].x, c0[r].y, c0[r].z, c0[r].w,
                              c1[r].x, c1[r].y, c1[r].z, c1[r].w,
                              c2[r].x, c2[r].y, c2[r].z, c2[r].w };
        const float tvk[4] = { tv[r].x, tv[r].y, tv[r].z, tv[r].w };
        dsum[r] = rs[r] = gs[r] = bs[r] = 0.0f;
        #pragma unroll
        for (int k = 0; k < 4; ++k) {
            dsum[r] += wi[r][k] * tvk[k];
            rs[r]   += wi[r][k] * c[3 * k + 0];
            gs[r]   += wi[r][k] * c[3 * k + 1];
            bs[r]   += wi[r][k] * c[3 * k + 2];
        }
    }
    #pragma unroll
    for (int off = 32; off > 0; off >>= 1) {
        #pragma unroll
        for (int r = 0; r < RPW; ++r) {
            dsum[r] += __shfl_xor(dsum[r], off, 64);
            rs[r]   += __shfl_xor(rs[r],   off, 64);
            gs[r]   += __shfl_xor(gs[r],   off, 64);
            bs[r]   += __shfl_xor(bs[r],   off, 64);
        }
    }

    if (lane == 0) {
        #pragma unroll
        for (int r = 0; r < RPW; ++r) {
            const int ray = ray0 + r;
            c_out[(size_t)ray * 3 + 0] = rs[r];
            c_out[(size_t)ray * 3 + 1] = gs[r];
            c_out[(size_t)ray * 3 + 2] = bs[r];
            d_out[ray] = dsum[r];
        }
    }
}

extern "C" void kernel_launch(void* const* d_in, const int* in_sizes, int n_in,
                              void* d_out, int out_size, void* d_ws, size_t ws_size,
                              hipStream_t stream) {
    const float* t     = (const float*)d_in[0];
    const float* sdf   = (const float*)d_in[1];
    const float* color = (const float*)d_in[2];
    const float* sil   = (const float*)d_in[3];
    float* out = (float*)d_out;

    const int blocks = N_RAYS / (4 * RPW);   // 4 waves/block, RPW rays/wave
    nerf_render_kernel<<<blocks, 256, 0, stream>>>(t, sdf, color, sil, out);
}

// Round 5
// 89.406 us; speedup vs baseline: 1.3037x; 1.0357x over previous
//
#include <hip/hip_runtime.h>

#define N_RAYS   65536
#define NS       256
#define NSM1     255
#define EPS_V    1e-5f
#define RPW      4   // rays per wave

typedef float f32x4 __attribute__((ext_vector_type(4)));

__device__ __forceinline__ float fast_rcp(float x) {
    return __builtin_amdgcn_rcpf(x);
}

// fast sigmoid(x) = 1/(1+exp(-x)) using native exp2 + rcp
__device__ __forceinline__ float fast_sigmoid(float x) {
    return fast_rcp(1.0f + __builtin_amdgcn_exp2f(-x * 1.442695041f));
}

__global__ __launch_bounds__(256) void nerf_render_kernel(
    const float* __restrict__ t,
    const float* __restrict__ sdf,
    const float* __restrict__ color,
    const float* __restrict__ s_inv_log,
    float* __restrict__ out)
{
    // Per-wave staging tiles for the flat redistribution of wi / t_out.
    // [wave][ray][sample]: b128 writes at lane*16B stride = conflict-free.
    __shared__ float lds_wi[4][RPW][NS];   // 16 KB
    __shared__ float lds_t [4][RPW][NS];   // 16 KB

    const int lane = threadIdx.x & 63;
    const int wv   = threadIdx.x >> 6;
    const int ray0 = blockIdx.x * (4 * RPW) + wv * RPW;

    float* __restrict__ c_out  = out;                               // 65536*3
    float* __restrict__ d_out  = out + (size_t)N_RAYS * 3;          // 65536
    float* __restrict__ wi_out = out + (size_t)N_RAYS * 4;          // 65536*255
    float* __restrict__ t_out  = wi_out + (size_t)N_RAYS * NSM1;    // 65536*255

    const float s = expf(-s_inv_log[0]);

    // ---- loads (all issued up front; 16B-aligned, fully coalesced) ----
    float4 sd[RPW], tv[RPW], c0[RPW], c1[RPW], c2[RPW];
    #pragma unroll
    for (int r = 0; r < RPW; ++r) {
        const size_t base = (size_t)(ray0 + r) * NS + (size_t)lane * 4;
        sd[r] = *reinterpret_cast<const float4*>(sdf + base);
        tv[r] = *reinterpret_cast<const float4*>(t   + base);
        const float4* cp = reinterpret_cast<const float4*>(color + base * 3);
        c0[r] = cp[0];
        c1[r] = cp[1];
        c2[r] = cp[2];
    }

    // ---- sigmoid, alpha, fused e*alpha (g) and local product L ----
    float g[RPW][4], Lp[RPW];
    #pragma unroll
    for (int r = 0; r < RPW; ++r) {
        float q[5];
        q[0] = fast_sigmoid(sd[r].x * s);
        q[1] = fast_sigmoid(sd[r].y * s);
        q[2] = fast_sigmoid(sd[r].z * s);
        q[3] = fast_sigmoid(sd[r].w * s);
        q[4] = __shfl_down(q[0], 1, 64);

        float ecur = 1.0f;
        #pragma unroll
        for (int k = 0; k < 4; ++k) {
            float a = (q[k] - q[k + 1] + EPS_V) * fast_rcp(q[k] + EPS_V);
            a = fminf(fmaxf(a, 0.0f), 1.0f);
            if (lane == 63 && k == 3) a = 0.0f;   // sample 255 has no alpha
            g[r][k] = ecur * a;                   // e[k] * alpha[k]
            ecur *= (1.0f - a);
        }
        Lp[r] = ecur;                             // product of (1-a) over 4
    }

    // ---- wave-wide exclusive product scan (4 independent chains) ----
    float p[RPW];
    #pragma unroll
    for (int r = 0; r < RPW; ++r) p[r] = Lp[r];
    #pragma unroll
    for (int off = 1; off < 64; off <<= 1) {
        #pragma unroll
        for (int r = 0; r < RPW; ++r) {
            float v = __shfl_up(p[r], off, 64);
            if (lane >= off) p[r] *= v;
        }
    }
    float Ew[RPW];
    #pragma unroll
    for (int r = 0; r < RPW; ++r) {
        Ew[r] = __shfl_up(p[r], 1, 64);
        if (lane == 0) Ew[r] = 1.0f;
    }

    // ---- wi; stage wi & t into LDS; per-lane partial sums ----
    float dsum[RPW], rs[RPW], gs[RPW], bs[RPW];
    #pragma unroll
    for (int r = 0; r < RPW; ++r) {
        float4 w4;
        w4.x = Ew[r] * g[r][0];
        w4.y = Ew[r] * g[r][1];
        w4.z = Ew[r] * g[r][2];
        w4.w = Ew[r] * g[r][3];

        *reinterpret_cast<float4*>(&lds_wi[wv][r][lane * 4]) = w4;
        *reinterpret_cast<float4*>(&lds_t [wv][r][lane * 4]) = tv[r];

        dsum[r] = w4.x * tv[r].x + w4.y * tv[r].y + w4.z * tv[r].z + w4.w * tv[r].w;
        rs[r] = w4.x * c0[r].x + w4.y * c0[r].w + w4.z * c1[r].z + w4.w * c2[r].y;
        gs[r] = w4.x * c0[r].y + w4.y * c1[r].x + w4.z * c1[r].w + w4.w * c2[r].z;
        bs[r] = w4.x * c0[r].z + w4.y * c1[r].y + w4.z * c2[r].x + w4.w * c2[r].w;
    }

    // ---- butterfly reductions (16 independent chains) ----
    #pragma unroll
    for (int off = 32; off > 0; off >>= 1) {
        #pragma unroll
        for (int r = 0; r < RPW; ++r) {
            dsum[r] += __shfl_xor(dsum[r], off, 64);
            rs[r]   += __shfl_xor(rs[r],   off, 64);
            gs[r]   += __shfl_xor(gs[r],   off, 64);
            bs[r]   += __shfl_xor(bs[r],   off, 64);
        }
    }
    if (lane == 0) {
        #pragma unroll
        for (int r = 0; r < RPW; ++r) {
            const int ray = ray0 + r;
            c_out[(size_t)ray * 3 + 0] = rs[r];
            c_out[(size_t)ray * 3 + 1] = gs[r];
            c_out[(size_t)ray * 3 + 2] = bs[r];
            d_out[ray] = dsum[r];
        }
    }

    // ---- flat redistribution: wave region = 4*255 = 1020 dwords = 255
    //      float4 chunks, 16B-aligned. Full-line nt vector stores ->
    //      writes bypass L2/L3 without partial-line amplification. ----
    float* wdst = wi_out + (size_t)ray0 * NSM1;
    float* tdst = t_out  + (size_t)ray0 * NSM1;
    #pragma unroll
    for (int it = 0; it < 4; ++it) {
        const int idx = it * 64 + lane;      // chunk index 0..254
        if (idx < 255) {
            const int p0 = idx * 4;          // flat dword offset
            float wa[4], ta[4];
            #pragma unroll
            for (int i = 0; i < 4; ++i) {
                const unsigned q  = (unsigned)(p0 + i);
                const unsigned dr = q / 255u;            // mulhi+shift
                const unsigned k  = q - dr * 255u;
                wa[i] = lds_wi[wv][dr][k];
                ta[i] = lds_t [wv][dr][k];
            }
            f32x4 w4 = { wa[0], wa[1], wa[2], wa[3] };
            f32x4 t4 = { ta[0], ta[1], ta[2], ta[3] };
            __builtin_nontemporal_store(w4, reinterpret_cast<f32x4*>(wdst + p0));
            __builtin_nontemporal_store(t4, reinterpret_cast<f32x4*>(tdst + p0));
        }
    }
}

extern "C" void kernel_launch(void* const* d_in, const int* in_sizes, int n_in,
                              void* d_out, int out_size, void* d_ws, size_t ws_size,
                              hipStream_t stream) {
    const float* t     = (const float*)d_in[0];
    const float* sdf   = (const float*)d_in[1];
    const float* color = (const float*)d_in[2];
    const float* sil   = (const float*)d_in[3];
    float* out = (float*)d_out;

    const int blocks = N_RAYS / (4 * RPW);   // 4 waves/block, RPW rays/wave
    nerf_render_kernel<<<blocks, 256, 0, stream>>>(t, sdf, color, sil, out);
}

// Round 6
// 86.306 us; speedup vs baseline: 1.3506x; 1.0359x over previous
//
#include <hip/hip_runtime.h>

#define N_RAYS   65536
#define NS       256
#define NSM1     255
#define EPS_V    1e-5f
#define RPW      4   // rays per wave

typedef float f32x4 __attribute__((ext_vector_type(4)));

__device__ __forceinline__ float fast_rcp(float x) {
    return __builtin_amdgcn_rcpf(x);
}

// fast sigmoid(x) = 1/(1+exp(-x)) using native exp2 + rcp
__device__ __forceinline__ float fast_sigmoid(float x) {
    return fast_rcp(1.0f + __builtin_amdgcn_exp2f(-x * 1.442695041f));
}

__global__ __launch_bounds__(256) void nerf_render_kernel(
    const float* __restrict__ t,
    const float* __restrict__ sdf,
    const float* __restrict__ color,
    const float* __restrict__ s_inv_log,
    float* __restrict__ out)
{
    // Wave-private staging for wi redistribution only (t_out is re-read from
    // the L1-hot t input instead of staged) -> 16 KB/block, 8 blocks/CU.
    __shared__ float lds_wi[4][RPW][NS];   // 16 KB

    const int lane = threadIdx.x & 63;
    const int wv   = threadIdx.x >> 6;
    const int ray0 = blockIdx.x * (4 * RPW) + wv * RPW;

    float* __restrict__ c_out  = out;                               // 65536*3
    float* __restrict__ d_out  = out + (size_t)N_RAYS * 3;          // 65536
    float* __restrict__ wi_out = out + (size_t)N_RAYS * 4;          // 65536*255
    float* __restrict__ t_out  = wi_out + (size_t)N_RAYS * NSM1;    // 65536*255

    const float s = expf(-s_inv_log[0]);

    // ---- loads (all issued up front; 16B-aligned, fully coalesced) ----
    float4 sd[RPW], tv[RPW], c0[RPW], c1[RPW], c2[RPW];
    #pragma unroll
    for (int r = 0; r < RPW; ++r) {
        const size_t base = (size_t)(ray0 + r) * NS + (size_t)lane * 4;
        sd[r] = *reinterpret_cast<const float4*>(sdf + base);
        tv[r] = *reinterpret_cast<const float4*>(t   + base);
        const float4* cp = reinterpret_cast<const float4*>(color + base * 3);
        c0[r] = cp[0];
        c1[r] = cp[1];
        c2[r] = cp[2];
    }

    // ---- sigmoid, alpha, fused e*alpha (g) and local product L ----
    float g[RPW][4], Lp[RPW];
    #pragma unroll
    for (int r = 0; r < RPW; ++r) {
        float q[5];
        q[0] = fast_sigmoid(sd[r].x * s);
        q[1] = fast_sigmoid(sd[r].y * s);
        q[2] = fast_sigmoid(sd[r].z * s);
        q[3] = fast_sigmoid(sd[r].w * s);
        q[4] = __shfl_down(q[0], 1, 64);

        float ecur = 1.0f;
        #pragma unroll
        for (int k = 0; k < 4; ++k) {
            float a = (q[k] - q[k + 1] + EPS_V) * fast_rcp(q[k] + EPS_V);
            a = fminf(fmaxf(a, 0.0f), 1.0f);
            if (lane == 63 && k == 3) a = 0.0f;   // sample 255 has no alpha
            g[r][k] = ecur * a;                   // e[k] * alpha[k]
            ecur *= (1.0f - a);
        }
        Lp[r] = ecur;                             // product of (1-a) over 4
    }

    // ---- wave-wide exclusive product scan (4 independent chains) ----
    float p[RPW];
    #pragma unroll
    for (int r = 0; r < RPW; ++r) p[r] = Lp[r];
    #pragma unroll
    for (int off = 1; off < 64; off <<= 1) {
        #pragma unroll
        for (int r = 0; r < RPW; ++r) {
            float v = __shfl_up(p[r], off, 64);
            if (lane >= off) p[r] *= v;
        }
    }
    float Ew[RPW];
    #pragma unroll
    for (int r = 0; r < RPW; ++r) {
        Ew[r] = __shfl_up(p[r], 1, 64);
        if (lane == 0) Ew[r] = 1.0f;
    }

    // ---- wi; stage wi into LDS (wave-private tile, no barrier needed);
    //      per-lane partial sums ----
    float dsum[RPW], rs[RPW], gs[RPW], bs[RPW];
    #pragma unroll
    for (int r = 0; r < RPW; ++r) {
        float4 w4;
        w4.x = Ew[r] * g[r][0];
        w4.y = Ew[r] * g[r][1];
        w4.z = Ew[r] * g[r][2];
        w4.w = Ew[r] * g[r][3];

        *reinterpret_cast<float4*>(&lds_wi[wv][r][lane * 4]) = w4;

        dsum[r] = w4.x * tv[r].x + w4.y * tv[r].y + w4.z * tv[r].z + w4.w * tv[r].w;
        rs[r] = w4.x * c0[r].x + w4.y * c0[r].w + w4.z * c1[r].z + w4.w * c2[r].y;
        gs[r] = w4.x * c0[r].y + w4.y * c1[r].x + w4.z * c1[r].w + w4.w * c2[r].z;
        bs[r] = w4.x * c0[r].z + w4.y * c1[r].y + w4.z * c2[r].x + w4.w * c2[r].w;
    }

    // ---- butterfly reductions (16 independent chains) ----
    #pragma unroll
    for (int off = 32; off > 0; off >>= 1) {
        #pragma unroll
        for (int r = 0; r < RPW; ++r) {
            dsum[r] += __shfl_xor(dsum[r], off, 64);
            rs[r]   += __shfl_xor(rs[r],   off, 64);
            gs[r]   += __shfl_xor(gs[r],   off, 64);
            bs[r]   += __shfl_xor(bs[r],   off, 64);
        }
    }
    if (lane == 0) {
        #pragma unroll
        for (int r = 0; r < RPW; ++r) {
            const int ray = ray0 + r;
            c_out[(size_t)ray * 3 + 0] = rs[r];
            c_out[(size_t)ray * 3 + 1] = gs[r];
            c_out[(size_t)ray * 3 + 2] = bs[r];
            d_out[ray] = dsum[r];
        }
    }

    // ---- flat redistribution: wave region = 4*255 = 1020 dwords = 255
    //      float4 chunks, 16B-aligned. wi comes from LDS; t comes straight
    //      from the t input (this wave just loaded that 4KB region -> L1-hot).
    //      Full-line contiguous nt vector stores. ----
    float* wdst = wi_out + (size_t)ray0 * NSM1;
    float* tdst = t_out  + (size_t)ray0 * NSM1;
    const float* tsrc = t + (size_t)ray0 * NS;
    #pragma unroll
    for (int it = 0; it < 4; ++it) {
        const int idx = it * 64 + lane;      // chunk index 0..254
        if (idx < 255) {
            const int p0 = idx * 4;          // flat dword offset in wave region
            float wa[4], ta[4];
            #pragma unroll
            for (int i = 0; i < 4; ++i) {
                const unsigned q  = (unsigned)(p0 + i);
                const unsigned dr = q / 255u;            // mulhi+shift
                const unsigned k  = q - dr * 255u;
                wa[i] = lds_wi[wv][dr][k];
                ta[i] = tsrc[dr * NS + k];               // L1-hot re-read
            }
            f32x4 w4 = { wa[0], wa[1], wa[2], wa[3] };
            f32x4 t4 = { ta[0], ta[1], ta[2], ta[3] };
            __builtin_nontemporal_store(w4, reinterpret_cast<f32x4*>(wdst + p0));
            __builtin_nontemporal_store(t4, reinterpret_cast<f32x4*>(tdst + p0));
        }
    }
}

extern "C" void kernel_launch(void* const* d_in, const int* in_sizes, int n_in,
                              void* d_out, int out_size, void* d_ws, size_t ws_size,
                              hipStream_t stream) {
    const float* t     = (const float*)d_in[0];
    const float* sdf   = (const float*)d_in[1];
    const float* color = (const float*)d_in[2];
    const float* sil   = (const float*)d_in[3];
    float* out = (float*)d_out;

    const int blocks = N_RAYS / (4 * RPW);   // 4 waves/block, RPW rays/wave
    nerf_render_kernel<<<blocks, 256, 0, stream>>>(t, sdf, color, sil, out);
}